// Round 15
// baseline (888.374 us; speedup 1.0000x reference)
//
#include <hip/hip_runtime.h>
#include <hip/hip_bf16.h>
#include <math.h>

#define N_NODES 100000
#define N_PAD   100096   // multiple of 256
#define N_EDGES 400000
#define IN_DIM  100
#define D       200
#define DP      208      // j padded to 13*16
#define KP      224      // k padded to 7*32
#define NUM_STEPS 4

// Truncated half-tile: 3 gates x (6 full t-blocks * 512 + t6 kq0 slice 128) = 9600
// shorts + 128 pad shorts (1216 x 16B chunks). A FULL jt tile = gi half + gh half.
#define HALF_SHORTS   9728
#define FULL_SHORTS   (2 * HALF_SHORTS)   // 19456 shorts = 38912 B
#define STAGE_GROUPS_FULL 38              // 19456 shorts / (64 lanes * 8 shorts)
#define GCAP          512          // per-wave edge-index LDS capacity in gather kernel
#define WCHUNKS_PER_SJT 2432       // 2 halves * 1216 chunks
#define WCONV_BLOCKS  494          // 4*13*2432 / 256

#define WTOT         (NUM_STEPS * 13 * 2 * HALF_SHORTS)   // 1,011,712 shorts per copy
#define NCOPIES      8
#define WREP_CHUNKS  ((NCOPIES - 1) * (WTOT / 8))         // 885,248 16B chunks
#define WREP_BLOCKS  (WREP_CHUNKS / 256)                  // 3458 exact

#define GRU_WAVES    8             // 512-thread gemm blocks: 8 waves x 32 rows = 256 rows
#define GRU_GRID     (N_PAD / 256) // 391 blocks, exact

typedef __attribute__((ext_vector_type(8))) short bfrag;   // 8 bf16 (4 VGPRs)
typedef __attribute__((ext_vector_type(4))) float facc;    // 4 fp32

// weights, NCOPIES physical replicas of the per-(step,jt) contiguous TRUNCATED tile.
__device__ short g_Wall[NCOPIES][WTOT];
__device__ float g_bias[6 * DP];

__device__ __forceinline__ float fast_sigmoid(float x) {
    return __builtin_amdgcn_rcpf(1.0f + __expf(-x));
}
__device__ __forceinline__ float fast_tanh(float x) {
    return 2.0f * __builtin_amdgcn_rcpf(1.0f + __expf(-2.0f * x)) - 1.0f;
}
__device__ __forceinline__ float bf2f(short u) {
    unsigned int x = ((unsigned int)(unsigned short)u) << 16;
    return __uint_as_float(x);
}

// ---------------- weight permute + Wc-fold + bias (writes copy 0) ----------------
// Compact layout per (s,jt,half): gate gg in 0..2 at gg*3200 shorts:
//   t<6: gg*3200 + t*512 + lane*8      (lane 0..63)
//   t=6: gg*3200 + 3072 + l*8          (l 0..15, kq=0 slice only; k>=200 is dead: A-side zero)
// chunks 1200..1215 of each half are zero padding.
__global__ __launch_bounds__(256) void wconv_kernel(const float* __restrict__ W,
                                                    const float* __restrict__ w_ih,
                                                    const float* __restrict__ w_hh,
                                                    const float* __restrict__ b_ih,
                                                    const float* __restrict__ b_hh) {
    if (blockIdx.x >= WCONV_BLOCKS) {
        int idx = (blockIdx.x - WCONV_BLOCKS) * 256 + threadIdx.x;
        if (idx < 6 * DP) {
            int g = idx / DP, j = idx % DP;
            float v = 0.0f;
            if (j < D) v = (g < 3) ? b_ih[g * 200 + j] : b_hh[(g - 3) * 200 + j];
            g_bias[idx] = v;
        }
        return;
    }
    int idx = blockIdx.x * 256 + threadIdx.x;   // chunk id < 4*13*2432 = 126464
    short* out = &g_Wall[0][0] + (size_t)idx * 8;
    int s    = idx / (13 * WCHUNKS_PER_SJT);
    int rem  = idx % (13 * WCHUNKS_PER_SJT);
    int jt   = rem / WCHUNKS_PER_SJT;
    int r2   = rem % WCHUNKS_PER_SJT;
    int half = r2 / 1216;
    int c    = r2 % 1216;
    if (c >= 1200) {                       // pad chunks: store zeros
        #pragma unroll
        for (int i = 0; i < 8; ++i) out[i] = 0;
        return;
    }
    int gg = c / 400, cc = c % 400;
    int t  = (cc < 384) ? (cc >> 6) : 6;
    int l  = (cc < 384) ? (cc & 63) : (cc - 384);
    int g  = half * 3 + gg;
    int j  = jt * 16 + (l & 15);
    int k0 = t * 32 + (l >> 4) * 8;
    float vals[8];
    if (g < 3) {
        // fold: vals[i] = dot(w_ih[g*200+j], W[s][k0+i])
        const float* wr = (j < D) ? &w_ih[(size_t)(g * 200 + j) * D] : nullptr;
        #pragma unroll
        for (int i = 0; i < 8; ++i) vals[i] = 0.0f;
        if (wr) {
            #pragma unroll
            for (int i = 0; i < 8; ++i) {
                int k = k0 + i;
                if (k < D) {
                    const float* Wr = &W[(size_t)s * D * D + (size_t)k * D];
                    float acc = 0.0f;
                    #pragma unroll 4
                    for (int tt = 0; tt < D; ++tt) acc += wr[tt] * Wr[tt];
                    vals[i] = acc;
                }
            }
        }
    } else {
        #pragma unroll
        for (int i = 0; i < 8; ++i) {
            int k = k0 + i;
            vals[i] = (j < D && k < D) ? w_hh[((size_t)(g - 3) * 200 + j) * D + k] : 0.0f;
        }
    }
    #pragma unroll
    for (int i = 0; i < 8; ++i) {
        __hip_bfloat16 b = __float2bfloat16(vals[i]);
        out[i] = *reinterpret_cast<short*>(&b);
    }
}

// ---------------- replicate copy 0 -> copies 1..7 (16B per thread) ----------------
__global__ __launch_bounds__(256) void wrep_kernel() {
    size_t idx = (size_t)blockIdx.x * 256 + threadIdx.x;   // < WREP_CHUNKS
    int copy = 1 + (int)(idx / (WTOT / 8));
    size_t off = (idx % (WTOT / 8)) * 8;
    *(ulonglong2*)&g_Wall[copy][off] = *(const ulonglong2*)&g_Wall[0][off];
}

// ---------------- pad: h[:, :100] = bf16(x), rest 0 ----------------
__global__ void pad_kernel(const float* __restrict__ x, __hip_bfloat16* __restrict__ h) {
    int idx = blockIdx.x * 256 + threadIdx.x;   // N_PAD*KP exact multiple of 256
    int n = idx / KP, c = idx % KP;
    float v = (n < N_NODES && c < IN_DIM) ? x[n * IN_DIM + c] : 0.0f;
    h[idx] = __float2bfloat16(v);
}

// ---------------- CSR build ----------------
__global__ void count_kernel(const int* __restrict__ dst, int* __restrict__ cnt) {
    int e = blockIdx.x * blockDim.x + threadIdx.x;
    if (e < N_EDGES) atomicAdd(&cnt[dst[e]], 1);
}

#define SCAN_B 1024
#define NB_SCAN ((N_NODES + SCAN_B - 1) / SCAN_B)   // 98
__global__ __launch_bounds__(SCAN_B) void scan1(const int* __restrict__ cnt,
                                                int* __restrict__ incl, int* __restrict__ bsum) {
    __shared__ int ws[16];
    int i = blockIdx.x * SCAN_B + threadIdx.x;
    int lane = threadIdx.x & 63, wid = threadIdx.x >> 6;
    int v = (i < N_NODES) ? cnt[i] : 0;
    int s = v;
    #pragma unroll
    for (int o = 1; o < 64; o <<= 1) {
        int t = __shfl_up(s, o, 64);
        if (lane >= o) s += t;
    }
    if (lane == 63) ws[wid] = s;
    __syncthreads();
    if (wid == 0) {
        int t = (lane < 16) ? ws[lane] : 0;
        #pragma unroll
        for (int o = 1; o < 16; o <<= 1) {
            int u = __shfl_up(t, o, 64);
            if (lane >= o) t += u;
        }
        if (lane < 16) ws[lane] = t;
    }
    __syncthreads();
    if (wid > 0) s += ws[wid - 1];
    if (i < N_NODES) incl[i] = s;
    if (threadIdx.x == SCAN_B - 1) bsum[blockIdx.x] = s;
}
__global__ void scan3(const int* __restrict__ cnt, const int* __restrict__ incl,
                      const int* __restrict__ bsum, int* __restrict__ off,
                      int* __restrict__ cursor) {
    __shared__ int sh[128];
    if (threadIdx.x < 128) sh[threadIdx.x] = (threadIdx.x < NB_SCAN) ? bsum[threadIdx.x] : 0;
    __syncthreads();
    for (int o = 1; o < 128; o <<= 1) {
        int t = (threadIdx.x >= o && threadIdx.x < 128) ? sh[threadIdx.x - o] : 0;
        __syncthreads();
        if (threadIdx.x < 128) sh[threadIdx.x] += t;
        __syncthreads();
    }
    int i = blockIdx.x * blockDim.x + threadIdx.x;
    if (i < N_NODES) {
        int b = i / SCAN_B;
        int pre = b ? sh[b - 1] : 0;
        int v = incl[i] - cnt[i] + pre;
        off[i] = v; cursor[i] = v;
    }
    if (i == 0) off[N_NODES] = N_EDGES;
}
__global__ void fill_kernel(const int* __restrict__ src, const int* __restrict__ dst,
                            int* __restrict__ cursor, int* __restrict__ esrc) {
    int e = blockIdx.x * blockDim.x + threadIdx.x;
    if (e < N_EDGES) {
        int pos = atomicAdd(&cursor[dst[e]], 1);
        esrc[pos] = src[e];
    }
}

// ---------------- async stage: one FULL jt tile (38912 B) global -> LDS ----------------
// striped across NW waves
__device__ __forceinline__ void stage_full(const short* __restrict__ gsrc,
                                           short* lds_dst, int wave, int lane, int nw) {
    for (int g = wave; g < STAGE_GROUPS_FULL; g += nw) {
        __builtin_amdgcn_global_load_lds(
            (const __attribute__((address_space(1))) void*)(gsrc + g * 512 + lane * 8),
            (__attribute__((address_space(3))) void*)(lds_dst + g * 512),
            16, 0, 0);
    }
}

// B-fragment read from a truncated staged half (base = gi half or gh half).
// t is compile-time (unrolled loops). t=6, lanes kq>=1: k>=200 where A-side is
// structurally zero -> supply zeros (NaN-safe).
__device__ __forceinline__ bfrag bv_load(const short* base, int g, int t, int lane) {
    if (t < 6) return *(const bfrag*)(base + g * 3200 + t * 512 + lane * 8);
    bfrag z;
    #pragma unroll
    for (int i = 0; i < 8; ++i) z[i] = 0;
    if (lane < 16) z = *(const bfrag*)(base + g * 3200 + 3072 + lane * 8);
    return z;
}

// ---------------- gather/aggregate kernel ----------------
// L3-random-row-BW-bound (~2.1 TB/s): time invariant to occupancy (grid 1564 vs 3128
// identical). Left as-is.
__global__ __launch_bounds__(256) void gather_kernel(const __hip_bfloat16* __restrict__ hcur,
                                                     __hip_bfloat16* __restrict__ Ascr,
                                                     const int* __restrict__ off,
                                                     const int* __restrict__ esrc) {
    __shared__ int EIdxAll[4 * GCAP];   // 8192 B
    int tid = threadIdx.x;
    int lane = tid & 63, wave = tid >> 6;
    int wbase = blockIdx.x * 32 + wave * 8;
    int* EIdx = EIdxAll + wave * GCAP;

    // prefetch this wave's contiguous esrc slice (CSR rows are contiguous)
    int nlo = wbase < N_NODES ? wbase : N_NODES;
    int nhi = (wbase + 8) < N_NODES ? (wbase + 8) : N_NODES;
    int lo = off[nlo];
    int cntw = off[nhi] - lo;
    bool use_lds = (cntw <= GCAP);
    if (use_lds)
        for (int i = lane; i < cntw; i += 64) EIdx[i] = esrc[lo + i];

    int r4 = lane >> 4;              // row-in-flight 0..3
    int ck = lane & 15;              // 16B chunk id (this lane also covers ck+16)
    int colA = ck * 8;
    int colB = colA + 128;           // (ck+16)*8
    bool sumB = (ck < 9);            // chunks 16..24 carry data (cols < 200)
    #pragma unroll
    for (int it = 0; it < 2; ++it) {
        int rr = it * 4 + r4;
        int n = wbase + rr;
        float a[8] = {0, 0, 0, 0, 0, 0, 0, 0};
        float b[8] = {0, 0, 0, 0, 0, 0, 0, 0};
        if (n < N_NODES) {
            int e0 = off[n] - lo, e1 = off[n + 1] - lo;
            int nb = (e1 - e0 + 3) >> 2;
            for (int bq = 0; bq < nb; ++bq) {
                int eb = e0 + bq * 4;
                int i0, i1, i2, i3;
                if (use_lds) {
                    i0 = EIdx[eb];
                    i1 = (eb + 1 < e1) ? EIdx[eb + 1] : N_NODES;
                    i2 = (eb + 2 < e1) ? EIdx[eb + 2] : N_NODES;
                    i3 = (eb + 3 < e1) ? EIdx[eb + 3] : N_NODES;
                } else {
                    i0 = esrc[lo + eb];
                    i1 = (eb + 1 < e1) ? esrc[lo + eb + 1] : N_NODES;
                    i2 = (eb + 2 < e1) ? esrc[lo + eb + 2] : N_NODES;
                    i3 = (eb + 3 < e1) ? esrc[lo + eb + 3] : N_NODES;
                }
                size_t s0 = (size_t)i0 * KP, s1 = (size_t)i1 * KP;
                size_t s2 = (size_t)i2 * KP, s3 = (size_t)i3 * KP;
                bfrag a0 = *(const bfrag*)(hcur + s0 + colA);
                bfrag a1 = *(const bfrag*)(hcur + s1 + colA);
                bfrag a2 = *(const bfrag*)(hcur + s2 + colA);
                bfrag a3 = *(const bfrag*)(hcur + s3 + colA);
                if (sumB) {
                    bfrag b0 = *(const bfrag*)(hcur + s0 + colB);
                    bfrag b1 = *(const bfrag*)(hcur + s1 + colB);
                    bfrag b2 = *(const bfrag*)(hcur + s2 + colB);
                    bfrag b3 = *(const bfrag*)(hcur + s3 + colB);
                    #pragma unroll
                    for (int q = 0; q < 8; ++q)
                        b[q] += (bf2f(b0[q]) + bf2f(b1[q])) + (bf2f(b2[q]) + bf2f(b3[q]));
                }
                #pragma unroll
                for (int q = 0; q < 8; ++q)
                    a[q] += (bf2f(a0[q]) + bf2f(a1[q])) + (bf2f(a2[q]) + bf2f(a3[q]));
            }
        }
        // pack + store (unconditional: rows >= N_NODES store zeros -> clean pad rows)
        __hip_bfloat16 oa[8], ob[8];
        #pragma unroll
        for (int q = 0; q < 8; ++q) {
            oa[q] = __float2bfloat16(a[q]);
            ob[q] = __float2bfloat16(b[q]);
        }
        __hip_bfloat16* arow = Ascr + (size_t)n * KP;
        *(ushort4*)(arow + colA)     = *(const ushort4*)&oa[0];
        *(ushort4*)(arow + colA + 4) = *(const ushort4*)&oa[4];
        if (ck < 12) {   // cols 128..223; cols 200..223 get zeros (b stayed 0)
            *(ushort4*)(arow + colB)     = *(const ushort4*)&ob[0];
            *(ushort4*)(arow + colB + 4) = *(const ushort4*)&ob[4];
        }
    }
}

// ---------------- MFMA GRU (+ pool on last step) ----------------
// v13 PHASE-SKEW TEST. Eight structural nulls (grid/residency/rounds/bytes/phasing/
// replication/load-order) all preserved one property: the 2 co-resident blocks per CU
// launch together, rounds are equal length -> they stay PHASE-LOCKED, stalling on
// their DMA-drain/barrier at the same instants (CU idle; all counters <25%). The one
// fast configuration (r0 fused, 173us for gather+gemm) had co-resident blocks at
// DIFFERENT phases. v13 de-phases the split gemm directly: odd blocks sleep ~half a
// round (~10.5k cycles via s_sleep) before the round loop; the offset persists
// (rounds are self-paced), so one block's stall window is covered by the other's
// compute window. One variable vs v12; zero correctness impact.
__global__ __launch_bounds__(512, 2) void gemm_gru(const __hip_bfloat16* __restrict__ hcur,
                                                   const __hip_bfloat16* __restrict__ Ascr,
                                                   __hip_bfloat16* __restrict__ hnext,
                                                   unsigned int* __restrict__ pooled,
                                                   int step) {
    __shared__ __align__(16) short Bs[2][FULL_SHORTS];  // 77824 B, weights only
    __shared__ unsigned int pmax[DP];                   // 832 B
    int tid = threadIdx.x;
    int lane = tid & 63, wave = tid >> 6;               // wave 0..7
    int mrow = lane & 15, kq = lane >> 4;
    int jcol = lane & 15;
    int rowq = (lane >> 4) * 4;
    bool dopool = (step == NUM_STEPS - 1);

    if (dopool) for (int c = tid; c < DP; c += 512) pmax[c] = 0u;

    const short* Wstep = &g_Wall[blockIdx.x & (NCOPIES - 1)][0]
                       + (size_t)step * 13 * (2 * HALF_SHORTS);
    int wbase = blockIdx.x * 256 + wave * 32;
    int phase = blockIdx.x % 13;            // de-phase: starting jt differs per block

    // round index r (0..12) -> rotated jt-tile base address
    auto jtptr = [&](int r) {
        int q = phase + r; if (q >= 13) q -= 13;
        return Wstep + (size_t)(2 * q) * HALF_SHORTS;
    };

    stage_full(jtptr(0), &Bs[0][0], wave, lane, GRU_WAVES);   // first jt-tile DMA ASAP

    // ---- A fragments from Ascr (direct, fragment-layout-contiguous) ----
    bfrag av[2][7], hv[2][7];
    #pragma unroll
    for (int p = 0; p < 2; ++p) {
        const __hip_bfloat16* arow = Ascr + (size_t)(wbase + p * 16 + mrow) * KP;
        #pragma unroll
        for (int t = 0; t < 7; ++t)
            av[p][t] = *(const bfrag*)(arow + t * 32 + kq * 8);
    }
    // ---- H fragments (resident; cols 200..223 are zero by construction) ----
    const __hip_bfloat16* hrow0 = hcur + (size_t)(wbase + mrow) * KP;
    const __hip_bfloat16* hrow1 = hrow0 + (size_t)16 * KP;
    #pragma unroll
    for (int t = 0; t < 7; ++t) {
        hv[0][t] = *(const bfrag*)(hrow0 + t * 32 + kq * 8);
        hv[1][t] = *(const bfrag*)(hrow1 + t * 32 + kq * 8);
    }

    // ---- PHASE SKEW: odd blocks delay ~half a round (~10.5k cycles) so the two
    // co-resident blocks on a CU alternate stall/compute windows instead of
    // stalling in lockstep. s_sleep has no memory/correctness effects.
    if (blockIdx.x & 1) {
        #pragma unroll
        for (int i = 0; i < 11; ++i) __builtin_amdgcn_s_sleep(15);
    }

    // acc[0]=r (gi+gh), acc[1]=z (gi+gh), acc[2]=i_n, acc[3]=h_n
    facc acc[4][2];
    unsigned short hold_u[2][4];

    for (int r = 0; r < 13; ++r) {
        __syncthreads();   // tile r DMA complete; buf[(r+1)&1] free for restage

        int jt = phase + r; if (jt >= 13) jt -= 13;
        int j = jt * 16 + jcol;

        // preload old-h for this jt's epilogue
        #pragma unroll
        for (int mf = 0; mf < 2; ++mf)
            #pragma unroll
            for (int q = 0; q < 4; ++q)
                hold_u[mf][q] = *(const unsigned short*)
                    (hcur + (size_t)(wbase + mf * 16 + rowq + q) * KP + j);

        // stage next tile (double-buffered; drained at next round's barrier)
        if (r + 1 < 13)
            stage_full(jtptr(r + 1), &Bs[(r + 1) & 1][0], wave, lane, GRU_WAVES);

        const short* Bgi = &Bs[r & 1][0];
        const short* Bgh = Bgi + HALF_SHORTS;

        #pragma unroll
        for (int g = 0; g < 4; ++g)
            #pragma unroll
            for (int mf = 0; mf < 2; ++mf) acc[g][mf] = (facc)(0.0f);

        // gi gates (r,z,n_i) consume av -> acc 0,1,2
        #pragma unroll
        for (int t = 0; t < 7; ++t) {
            bfrag bv[3];
            #pragma unroll
            for (int g = 0; g < 3; ++g) bv[g] = bv_load(Bgi, g, t, lane);
            #pragma unroll
            for (int g = 0; g < 3; ++g)
                #pragma unroll
                for (int mf = 0; mf < 2; ++mf)
                    acc[g][mf] = __builtin_amdgcn_mfma_f32_16x16x32_bf16(av[mf][t], bv[g], acc[g][mf], 0, 0, 0);
        }
        // gh gates (r,z,n_h) consume hv -> acc 0,1 (merged) and 3
        #pragma unroll
        for (int t = 0; t < 7; ++t) {
            bfrag bv[3];
            #pragma unroll
            for (int g = 0; g < 3; ++g) bv[g] = bv_load(Bgh, g, t, lane);
            #pragma unroll
            for (int mf = 0; mf < 2; ++mf) {
                acc[0][mf] = __builtin_amdgcn_mfma_f32_16x16x32_bf16(hv[mf][t], bv[0], acc[0][mf], 0, 0, 0);
                acc[1][mf] = __builtin_amdgcn_mfma_f32_16x16x32_bf16(hv[mf][t], bv[1], acc[1][mf], 0, 0, 0);
                acc[3][mf] = __builtin_amdgcn_mfma_f32_16x16x32_bf16(hv[mf][t], bv[2], acc[3][mf], 0, 0, 0);
            }
        }

        // epilogue: C/D layout col=lane&15 (j), row=(lane>>4)*4+reg (m)
        float tmax = 0.0f;
        if (j < D) {
            float bir = g_bias[j],          biz = g_bias[DP + j],     bin = g_bias[2 * DP + j];
            float bhr = g_bias[3 * DP + j], bhz = g_bias[4 * DP + j], bhn = g_bias[5 * DP + j];
            #pragma unroll
            for (int mf = 0; mf < 2; ++mf) {
                int m0 = wbase + mf * 16 + rowq;
                #pragma unroll
                for (int q = 0; q < 4; ++q) {
                    int m = m0 + q;
                    if (m < N_NODES) {
                        float hold = bf2f((short)hold_u[mf][q]);
                        float rr = fast_sigmoid(acc[0][mf][q] + bir + bhr);
                        float zz = fast_sigmoid(acc[1][mf][q] + biz + bhz);
                        float nn = fast_tanh(acc[2][mf][q] + bin + rr * (acc[3][mf][q] + bhn));
                        float hv2 = (1.0f - zz) * nn + zz * hold;
                        hnext[(size_t)m * KP + j] = __float2bfloat16(hv2);
                        if (hv2 > tmax) tmax = hv2;
                    }
                }
            }
            if (dopool) atomicMax(&pmax[j], __float_as_uint(tmax));
        }
    }

    if (dopool) {
        __syncthreads();
        for (int c = tid; c < D; c += 512) atomicMax(&pooled[c], pmax[c]);
    }
}

// ---------------- logits + softmax ----------------
__global__ void head_kernel(const unsigned int* __restrict__ pooled,
                            const float* __restrict__ cls_w,
                            const float* __restrict__ cls_b,
                            float* __restrict__ out) {
    if (threadIdx.x == 0) {
        float l0 = cls_b[0], l1 = cls_b[1];
        for (int d = 0; d < D; ++d) {
            float p = __uint_as_float(pooled[d]);
            l0 += p * cls_w[d];
            l1 += p * cls_w[D + d];
        }
        float mx = l0 > l1 ? l0 : l1;
        float e0 = expf(l0 - mx), e1 = expf(l1 - mx);
        out[0] = e0 / (e0 + e1);
        out[1] = e1 / (e0 + e1);
    }
}

extern "C" void kernel_launch(void* const* d_in, const int* in_sizes, int n_in,
                              void* d_out, int out_size, void* d_ws, size_t ws_size,
                              hipStream_t stream) {
    const float* x     = (const float*)d_in[0];
    const float* W     = (const float*)d_in[1];
    const float* w_ih  = (const float*)d_in[2];
    const float* w_hh  = (const float*)d_in[3];
    const float* b_ih  = (const float*)d_in[4];
    const float* b_hh  = (const float*)d_in[5];
    const float* cls_w = (const float*)d_in[6];
    const float* cls_b = (const float*)d_in[7];
    const int*   ei    = (const int*)d_in[8];
    const int* src = ei;
    const int* dst = ei + N_EDGES;

    const size_t ROWB = (size_t)N_PAD * KP;     // bf16 elements per buffer
    __hip_bfloat16* hA   = (__hip_bfloat16*)d_ws;
    __hip_bfloat16* hB   = hA + ROWB;
    __hip_bfloat16* Ascr = hB + ROWB;           // aggregated-message scratch (3rd buffer)
    int* cnt    = (int*)(Ascr + ROWB);
    int* incl   = cnt + N_NODES;
    int* bsum   = incl + N_NODES;
    int* off    = bsum + 128;
    int* cursor = off + N_NODES + 1;
    int* esrc   = cursor + N_NODES;
    unsigned int* pooled = (unsigned int*)(esrc + N_EDGES);

    // CSR build (once per call; edges are step-invariant)
    hipMemsetAsync(cnt, 0, N_NODES * sizeof(int), stream);
    count_kernel<<<(N_EDGES + 255) / 256, 256, 0, stream>>>(dst, cnt);
    scan1<<<NB_SCAN, SCAN_B, 0, stream>>>(cnt, incl, bsum);
    scan3<<<(N_NODES + 255) / 256, 256, 0, stream>>>(cnt, incl, bsum, off, cursor);
    fill_kernel<<<(N_EDGES + 255) / 256, 256, 0, stream>>>(src, dst, cursor, esrc);

    // weight prep: permute+fold into copy 0, then replicate to copies 1..7
    wconv_kernel<<<WCONV_BLOCKS + 5, 256, 0, stream>>>(W, w_ih, w_hh, b_ih, b_hh);
    wrep_kernel<<<WREP_BLOCKS, 256, 0, stream>>>();

    pad_kernel<<<(int)(ROWB / 256), 256, 0, stream>>>(x, hA);
    // hB fully zeroed once: (a) gather's clamped batches read zero-row N_NODES on
    // odd steps, (b) cols 200..223 stay zero forever -> hv t=6 is a plain load.
    hipMemsetAsync(hB, 0, ROWB * sizeof(__hip_bfloat16), stream);
    hipMemsetAsync(pooled, 0, D * sizeof(unsigned int), stream);

    __hip_bfloat16* hcur = hA;
    __hip_bfloat16* hnext = hB;
    for (int s = 0; s < NUM_STEPS; ++s) {
        gather_kernel<<<N_PAD / 32, 256, 0, stream>>>(hcur, Ascr, off, esrc);
        gemm_gru<<<GRU_GRID, 512, 0, stream>>>(hcur, Ascr, hnext, pooled, s);
        __hip_bfloat16* t = hcur; hcur = hnext; hnext = t;
    }
    head_kernel<<<1, 64, 0, stream>>>(pooled, cls_w, cls_b, (float*)d_out);
}

// Round 16
// 829.595 us; speedup vs baseline: 1.0709x; 1.0709x over previous
//
#include <hip/hip_runtime.h>
#include <hip/hip_bf16.h>
#include <math.h>

#define N_NODES 100000
#define N_PAD   100096   // multiple of 256
#define N_EDGES 400000
#define IN_DIM  100
#define D       200
#define DP      208      // j padded to 13*16
#define KP      224      // k padded to 7*32
#define NUM_STEPS 4

// Truncated half-tile: 3 gates x (6 full t-blocks * 512 + t6 kq0 slice 128) = 9600
// shorts + 128 pad shorts (1216 x 16B chunks). A FULL jt tile = gi half + gh half.
#define HALF_SHORTS   9728
#define FULL_SHORTS   (2 * HALF_SHORTS)   // 19456 shorts = 38912 B
#define STAGE_GROUPS_FULL 38              // 19456 shorts / (64 lanes * 8 shorts)
#define GCAP          512          // per-wave edge-index LDS capacity in gather kernel
#define WCHUNKS_PER_SJT 2432       // 2 halves * 1216 chunks
#define WCONV_BLOCKS  494          // 4*13*2432 / 256

#define GRU_WAVES    8             // 512-thread gemm blocks: 8 waves x 32 rows = 256 rows
#define GRU_GRID     (N_PAD / 256) // 391 blocks, exact

typedef __attribute__((ext_vector_type(8))) short bfrag;   // 8 bf16 (4 VGPRs)
typedef __attribute__((ext_vector_type(4))) float facc;    // 4 fp32

// weights, per-(step,jt) contiguous TRUNCATED tile: [s][jt][half2][gg3][t-compact]
__device__ short g_Wall[NUM_STEPS * 13 * 2 * HALF_SHORTS];
__device__ float g_bias[6 * DP];

__device__ __forceinline__ float fast_sigmoid(float x) {
    return __builtin_amdgcn_rcpf(1.0f + __expf(-x));
}
__device__ __forceinline__ float fast_tanh(float x) {
    return 2.0f * __builtin_amdgcn_rcpf(1.0f + __expf(-2.0f * x)) - 1.0f;
}
__device__ __forceinline__ float bf2f(short u) {
    unsigned int x = ((unsigned int)(unsigned short)u) << 16;
    return __uint_as_float(x);
}

// ---------------- weight permute + Wc-fold + bias, all in one kernel ----------------
// Compact layout per (s,jt,half): gate gg in 0..2 at gg*3200 shorts:
//   t<6: gg*3200 + t*512 + lane*8      (lane 0..63)
//   t=6: gg*3200 + 3072 + l*8          (l 0..15, kq=0 slice only; k>=200 is dead: A-side zero)
// chunks 1200..1215 of each half are zero padding.
__global__ __launch_bounds__(256) void wconv_kernel(const float* __restrict__ W,
                                                    const float* __restrict__ w_ih,
                                                    const float* __restrict__ w_hh,
                                                    const float* __restrict__ b_ih,
                                                    const float* __restrict__ b_hh) {
    if (blockIdx.x >= WCONV_BLOCKS) {
        int idx = (blockIdx.x - WCONV_BLOCKS) * 256 + threadIdx.x;
        if (idx < 6 * DP) {
            int g = idx / DP, j = idx % DP;
            float v = 0.0f;
            if (j < D) v = (g < 3) ? b_ih[g * 200 + j] : b_hh[(g - 3) * 200 + j];
            g_bias[idx] = v;
        }
        return;
    }
    int idx = blockIdx.x * 256 + threadIdx.x;   // chunk id < 4*13*2432 = 126464
    short* out = g_Wall + (size_t)idx * 8;
    int s    = idx / (13 * WCHUNKS_PER_SJT);
    int rem  = idx % (13 * WCHUNKS_PER_SJT);
    int jt   = rem / WCHUNKS_PER_SJT;
    int r2   = rem % WCHUNKS_PER_SJT;
    int half = r2 / 1216;
    int c    = r2 % 1216;
    if (c >= 1200) {                       // pad chunks: store zeros
        #pragma unroll
        for (int i = 0; i < 8; ++i) out[i] = 0;
        return;
    }
    int gg = c / 400, cc = c % 400;
    int t  = (cc < 384) ? (cc >> 6) : 6;
    int l  = (cc < 384) ? (cc & 63) : (cc - 384);
    int g  = half * 3 + gg;
    int j  = jt * 16 + (l & 15);
    int k0 = t * 32 + (l >> 4) * 8;
    float vals[8];
    if (g < 3) {
        // fold: vals[i] = dot(w_ih[g*200+j], W[s][k0+i])
        const float* wr = (j < D) ? &w_ih[(size_t)(g * 200 + j) * D] : nullptr;
        #pragma unroll
        for (int i = 0; i < 8; ++i) vals[i] = 0.0f;
        if (wr) {
            #pragma unroll
            for (int i = 0; i < 8; ++i) {
                int k = k0 + i;
                if (k < D) {
                    const float* Wr = &W[(size_t)s * D * D + (size_t)k * D];
                    float acc = 0.0f;
                    #pragma unroll 4
                    for (int tt = 0; tt < D; ++tt) acc += wr[tt] * Wr[tt];
                    vals[i] = acc;
                }
            }
        }
    } else {
        #pragma unroll
        for (int i = 0; i < 8; ++i) {
            int k = k0 + i;
            vals[i] = (j < D && k < D) ? w_hh[((size_t)(g - 3) * 200 + j) * D + k] : 0.0f;
        }
    }
    #pragma unroll
    for (int i = 0; i < 8; ++i) {
        __hip_bfloat16 b = __float2bfloat16(vals[i]);
        out[i] = *reinterpret_cast<short*>(&b);
    }
}

// ---------------- pad: h[:, :100] = bf16(x), rest 0 ----------------
__global__ void pad_kernel(const float* __restrict__ x, __hip_bfloat16* __restrict__ h) {
    int idx = blockIdx.x * 256 + threadIdx.x;   // N_PAD*KP exact multiple of 256
    int n = idx / KP, c = idx % KP;
    float v = (n < N_NODES && c < IN_DIM) ? x[n * IN_DIM + c] : 0.0f;
    h[idx] = __float2bfloat16(v);
}

// ---------------- CSR build ----------------
__global__ void count_kernel(const int* __restrict__ dst, int* __restrict__ cnt) {
    int e = blockIdx.x * blockDim.x + threadIdx.x;
    if (e < N_EDGES) atomicAdd(&cnt[dst[e]], 1);
}

#define SCAN_B 1024
#define NB_SCAN ((N_NODES + SCAN_B - 1) / SCAN_B)   // 98
__global__ __launch_bounds__(SCAN_B) void scan1(const int* __restrict__ cnt,
                                                int* __restrict__ incl, int* __restrict__ bsum) {
    __shared__ int ws[16];
    int i = blockIdx.x * SCAN_B + threadIdx.x;
    int lane = threadIdx.x & 63, wid = threadIdx.x >> 6;
    int v = (i < N_NODES) ? cnt[i] : 0;
    int s = v;
    #pragma unroll
    for (int o = 1; o < 64; o <<= 1) {
        int t = __shfl_up(s, o, 64);
        if (lane >= o) s += t;
    }
    if (lane == 63) ws[wid] = s;
    __syncthreads();
    if (wid == 0) {
        int t = (lane < 16) ? ws[lane] : 0;
        #pragma unroll
        for (int o = 1; o < 16; o <<= 1) {
            int u = __shfl_up(t, o, 64);
            if (lane >= o) t += u;
        }
        if (lane < 16) ws[lane] = t;
    }
    __syncthreads();
    if (wid > 0) s += ws[wid - 1];
    if (i < N_NODES) incl[i] = s;
    if (threadIdx.x == SCAN_B - 1) bsum[blockIdx.x] = s;
}
__global__ void scan3(const int* __restrict__ cnt, const int* __restrict__ incl,
                      const int* __restrict__ bsum, int* __restrict__ off,
                      int* __restrict__ cursor) {
    __shared__ int sh[128];
    if (threadIdx.x < 128) sh[threadIdx.x] = (threadIdx.x < NB_SCAN) ? bsum[threadIdx.x] : 0;
    __syncthreads();
    for (int o = 1; o < 128; o <<= 1) {
        int t = (threadIdx.x >= o && threadIdx.x < 128) ? sh[threadIdx.x - o] : 0;
        __syncthreads();
        if (threadIdx.x < 128) sh[threadIdx.x] += t;
        __syncthreads();
    }
    int i = blockIdx.x * blockDim.x + threadIdx.x;
    if (i < N_NODES) {
        int b = i / SCAN_B;
        int pre = b ? sh[b - 1] : 0;
        int v = incl[i] - cnt[i] + pre;
        off[i] = v; cursor[i] = v;
    }
    if (i == 0) off[N_NODES] = N_EDGES;
}
__global__ void fill_kernel(const int* __restrict__ src, const int* __restrict__ dst,
                            int* __restrict__ cursor, int* __restrict__ esrc) {
    int e = blockIdx.x * blockDim.x + threadIdx.x;
    if (e < N_EDGES) {
        int pos = atomicAdd(&cursor[dst[e]], 1);
        esrc[pos] = src[e];
    }
}

// ---------------- async stage: one FULL jt tile (38912 B) global -> LDS ----------------
// striped across NW waves
__device__ __forceinline__ void stage_full(const short* __restrict__ gsrc,
                                           short* lds_dst, int wave, int lane, int nw) {
    for (int g = wave; g < STAGE_GROUPS_FULL; g += nw) {
        __builtin_amdgcn_global_load_lds(
            (const __attribute__((address_space(1))) void*)(gsrc + g * 512 + lane * 8),
            (__attribute__((address_space(3))) void*)(lds_dst + g * 512),
            16, 0, 0);
    }
}

// B-fragment read from a truncated staged half (base = gi half or gh half).
// t is compile-time (unrolled loops). t=6, lanes kq>=1: k>=200 where A-side is
// structurally zero -> supply zeros (NaN-safe).
__device__ __forceinline__ bfrag bv_load(const short* base, int g, int t, int lane) {
    if (t < 6) return *(const bfrag*)(base + g * 3200 + t * 512 + lane * 8);
    bfrag z;
    #pragma unroll
    for (int i = 0; i < 8; ++i) z[i] = 0;
    if (lane < 16) z = *(const bfrag*)(base + g * 3200 + 3072 + lane * 8);
    return z;
}

// one 4-edge batch for one row: load + accumulate (clamped edges read zero-row N_NODES)
__device__ __forceinline__ void gather_batch(const __hip_bfloat16* __restrict__ hcur,
                                             const int* __restrict__ EIdx,
                                             const int* __restrict__ esrc,
                                             int lo, bool use_lds, int eb, int e1,
                                             int colA, int colB, bool sumB,
                                             float a[8], float b[8]) {
    int i0, i1, i2, i3;
    if (use_lds) {
        i0 = EIdx[eb];
        i1 = (eb + 1 < e1) ? EIdx[eb + 1] : N_NODES;
        i2 = (eb + 2 < e1) ? EIdx[eb + 2] : N_NODES;
        i3 = (eb + 3 < e1) ? EIdx[eb + 3] : N_NODES;
    } else {
        i0 = esrc[lo + eb];
        i1 = (eb + 1 < e1) ? esrc[lo + eb + 1] : N_NODES;
        i2 = (eb + 2 < e1) ? esrc[lo + eb + 2] : N_NODES;
        i3 = (eb + 3 < e1) ? esrc[lo + eb + 3] : N_NODES;
    }
    size_t s0 = (size_t)i0 * KP, s1 = (size_t)i1 * KP;
    size_t s2 = (size_t)i2 * KP, s3 = (size_t)i3 * KP;
    bfrag a0 = *(const bfrag*)(hcur + s0 + colA);
    bfrag a1 = *(const bfrag*)(hcur + s1 + colA);
    bfrag a2 = *(const bfrag*)(hcur + s2 + colA);
    bfrag a3 = *(const bfrag*)(hcur + s3 + colA);
    if (sumB) {
        bfrag b0 = *(const bfrag*)(hcur + s0 + colB);
        bfrag b1 = *(const bfrag*)(hcur + s1 + colB);
        bfrag b2 = *(const bfrag*)(hcur + s2 + colB);
        bfrag b3 = *(const bfrag*)(hcur + s3 + colB);
        #pragma unroll
        for (int q = 0; q < 8; ++q)
            b[q] += (bf2f(b0[q]) + bf2f(b1[q])) + (bf2f(b2[q]) + bf2f(b3[q]));
    }
    #pragma unroll
    for (int q = 0; q < 8; ++q)
        a[q] += (bf2f(a0[q]) + bf2f(a1[q])) + (bf2f(a2[q]) + bf2f(a3[q]));
}

// ---------------- gather/aggregate kernel ----------------
// v14 MLP FIX: the old kernel processed its two rows in two SEQUENTIAL runtime loops
// -> one dependent load->accumulate chain at a time (~2 loads in flight/lane),
// latency-bound on L3-resident random rows. Now both rows run INTERLEAVED in one
// fused loop with independent accumulators -> 2x independent chains, ~2x outstanding
// requests. (Same lever that made split-gather 2x faster than fused: parallelism in
// flight, not BW.) Stores unchanged (pad rows write zeros).
__global__ __launch_bounds__(256) void gather_kernel(const __hip_bfloat16* __restrict__ hcur,
                                                     __hip_bfloat16* __restrict__ Ascr,
                                                     const int* __restrict__ off,
                                                     const int* __restrict__ esrc) {
    __shared__ int EIdxAll[4 * GCAP];   // 8192 B
    int tid = threadIdx.x;
    int lane = tid & 63, wave = tid >> 6;
    int wbase = blockIdx.x * 32 + wave * 8;
    int* EIdx = EIdxAll + wave * GCAP;

    // prefetch this wave's contiguous esrc slice (CSR rows are contiguous)
    int nlo = wbase < N_NODES ? wbase : N_NODES;
    int nhi = (wbase + 8) < N_NODES ? (wbase + 8) : N_NODES;
    int lo = off[nlo];
    int cntw = off[nhi] - lo;
    bool use_lds = (cntw <= GCAP);
    if (use_lds)
        for (int i = lane; i < cntw; i += 64) EIdx[i] = esrc[lo + i];

    int r4 = lane >> 4;              // row-group 0..3
    int ck = lane & 15;              // 16B chunk id (this lane also covers ck+16)
    int colA = ck * 8;
    int colB = colA + 128;           // (ck+16)*8
    bool sumB = (ck < 9);            // chunks 16..24 carry data (cols < 200)

    int nA = wbase + r4;             // rows r4 and r4+4, processed interleaved
    int nB = wbase + 4 + r4;
    float aA[8] = {0,0,0,0,0,0,0,0}, bA[8] = {0,0,0,0,0,0,0,0};
    float aB[8] = {0,0,0,0,0,0,0,0}, bB[8] = {0,0,0,0,0,0,0,0};
    int eA0 = 0, eA1 = 0, eB0 = 0, eB1 = 0;
    if (nA < N_NODES) { eA0 = off[nA] - lo; eA1 = off[nA + 1] - lo; }
    if (nB < N_NODES) { eB0 = off[nB] - lo; eB1 = off[nB + 1] - lo; }
    int nbA = (eA1 - eA0 + 3) >> 2;
    int nbB = (eB1 - eB0 + 3) >> 2;
    int nb = nbA > nbB ? nbA : nbB;

    for (int bq = 0; bq < nb; ++bq) {
        if (bq < nbA)
            gather_batch(hcur, EIdx, esrc, lo, use_lds, eA0 + bq * 4, eA1,
                         colA, colB, sumB, aA, bA);
        if (bq < nbB)
            gather_batch(hcur, EIdx, esrc, lo, use_lds, eB0 + bq * 4, eB1,
                         colA, colB, sumB, aB, bB);
    }

    // pack + store both rows (unconditional: rows >= N_NODES store zeros)
    __hip_bfloat16 oa[8], ob[8];
    #pragma unroll
    for (int q = 0; q < 8; ++q) { oa[q] = __float2bfloat16(aA[q]); ob[q] = __float2bfloat16(bA[q]); }
    __hip_bfloat16* arowA = Ascr + (size_t)nA * KP;
    *(ushort4*)(arowA + colA)     = *(const ushort4*)&oa[0];
    *(ushort4*)(arowA + colA + 4) = *(const ushort4*)&oa[4];
    if (ck < 12) {
        *(ushort4*)(arowA + colB)     = *(const ushort4*)&ob[0];
        *(ushort4*)(arowA + colB + 4) = *(const ushort4*)&ob[4];
    }
    #pragma unroll
    for (int q = 0; q < 8; ++q) { oa[q] = __float2bfloat16(aB[q]); ob[q] = __float2bfloat16(bB[q]); }
    __hip_bfloat16* arowB = Ascr + (size_t)nB * KP;
    *(ushort4*)(arowB + colA)     = *(const ushort4*)&oa[0];
    *(ushort4*)(arowB + colA + 4) = *(const ushort4*)&oa[4];
    if (ck < 12) {
        *(ushort4*)(arowB + colB)     = *(const ushort4*)&ob[0];
        *(ushort4*)(arowB + colB + 4) = *(const ushort4*)&ob[4];
    }
}

// ---------------- MFMA GRU (+ pool on last step) ----------------
// Round-11 v10 structure EXACTLY (best measured total 830.7us): 512 threads, 8 waves
// x 32 rows, grid 391, 13 full-tile rounds, stage-first order, LDS 78.7KB, (512,2).
// Nine structural experiments on this kernel (grid/residency/rounds/bytes/de-phasing/
// replication/load-order/phase-skew) were all null: its ~118us is a per-block DMA+
// barrier serial floor not reachable from HIP source. Left as the best-known config.
__global__ __launch_bounds__(512, 2) void gemm_gru(const __hip_bfloat16* __restrict__ hcur,
                                                   const __hip_bfloat16* __restrict__ Ascr,
                                                   __hip_bfloat16* __restrict__ hnext,
                                                   unsigned int* __restrict__ pooled,
                                                   int step) {
    __shared__ __align__(16) short Bs[2][FULL_SHORTS];  // 77824 B, weights only
    __shared__ unsigned int pmax[DP];                   // 832 B
    int tid = threadIdx.x;
    int lane = tid & 63, wave = tid >> 6;               // wave 0..7
    int mrow = lane & 15, kq = lane >> 4;
    int jcol = lane & 15;
    int rowq = (lane >> 4) * 4;
    bool dopool = (step == NUM_STEPS - 1);

    if (dopool) for (int c = tid; c < DP; c += 512) pmax[c] = 0u;

    const short* Wstep = g_Wall + (size_t)step * 13 * (2 * HALF_SHORTS);
    int wbase = blockIdx.x * 256 + wave * 32;
    int phase = blockIdx.x % 13;            // de-phase: starting jt differs per block

    // round index r (0..12) -> rotated jt-tile base address
    auto jtptr = [&](int r) {
        int q = phase + r; if (q >= 13) q -= 13;
        return Wstep + (size_t)(2 * q) * HALF_SHORTS;
    };

    stage_full(jtptr(0), &Bs[0][0], wave, lane, GRU_WAVES);   // first jt-tile DMA ASAP

    // ---- A fragments from Ascr (direct, fragment-layout-contiguous) ----
    bfrag av[2][7], hv[2][7];
    #pragma unroll
    for (int p = 0; p < 2; ++p) {
        const __hip_bfloat16* arow = Ascr + (size_t)(wbase + p * 16 + mrow) * KP;
        #pragma unroll
        for (int t = 0; t < 7; ++t)
            av[p][t] = *(const bfrag*)(arow + t * 32 + kq * 8);
    }
    // ---- H fragments (resident; cols 200..223 are zero by construction) ----
    const __hip_bfloat16* hrow0 = hcur + (size_t)(wbase + mrow) * KP;
    const __hip_bfloat16* hrow1 = hrow0 + (size_t)16 * KP;
    #pragma unroll
    for (int t = 0; t < 7; ++t) {
        hv[0][t] = *(const bfrag*)(hrow0 + t * 32 + kq * 8);
        hv[1][t] = *(const bfrag*)(hrow1 + t * 32 + kq * 8);
    }

    // acc[0]=r (gi+gh), acc[1]=z (gi+gh), acc[2]=i_n, acc[3]=h_n
    facc acc[4][2];
    unsigned short hold_u[2][4];

    for (int r = 0; r < 13; ++r) {
        __syncthreads();   // tile r DMA complete; buf[(r+1)&1] free for restage
        if (r + 1 < 13)
            stage_full(jtptr(r + 1), &Bs[(r + 1) & 1][0], wave, lane, GRU_WAVES);

        int jt = phase + r; if (jt >= 13) jt -= 13;
        int j = jt * 16 + jcol;
        const short* Bgi = &Bs[r & 1][0];
        const short* Bgh = Bgi + HALF_SHORTS;

        // preload old-h for this jt's epilogue (latency hides under gi+gh compute)
        #pragma unroll
        for (int mf = 0; mf < 2; ++mf)
            #pragma unroll
            for (int q = 0; q < 4; ++q)
                hold_u[mf][q] = *(const unsigned short*)
                    (hcur + (size_t)(wbase + mf * 16 + rowq + q) * KP + j);
        #pragma unroll
        for (int g = 0; g < 4; ++g)
            #pragma unroll
            for (int mf = 0; mf < 2; ++mf) acc[g][mf] = (facc)(0.0f);

        // gi gates (r,z,n_i) consume av -> acc 0,1,2
        #pragma unroll
        for (int t = 0; t < 7; ++t) {
            bfrag bv[3];
            #pragma unroll
            for (int g = 0; g < 3; ++g) bv[g] = bv_load(Bgi, g, t, lane);
            #pragma unroll
            for (int g = 0; g < 3; ++g)
                #pragma unroll
                for (int mf = 0; mf < 2; ++mf)
                    acc[g][mf] = __builtin_amdgcn_mfma_f32_16x16x32_bf16(av[mf][t], bv[g], acc[g][mf], 0, 0, 0);
        }
        // gh gates (r,z,n_h) consume hv -> acc 0,1 (merged) and 3
        #pragma unroll
        for (int t = 0; t < 7; ++t) {
            bfrag bv[3];
            #pragma unroll
            for (int g = 0; g < 3; ++g) bv[g] = bv_load(Bgh, g, t, lane);
            #pragma unroll
            for (int mf = 0; mf < 2; ++mf) {
                acc[0][mf] = __builtin_amdgcn_mfma_f32_16x16x32_bf16(hv[mf][t], bv[0], acc[0][mf], 0, 0, 0);
                acc[1][mf] = __builtin_amdgcn_mfma_f32_16x16x32_bf16(hv[mf][t], bv[1], acc[1][mf], 0, 0, 0);
                acc[3][mf] = __builtin_amdgcn_mfma_f32_16x16x32_bf16(hv[mf][t], bv[2], acc[3][mf], 0, 0, 0);
            }
        }

        // epilogue: C/D layout col=lane&15 (j), row=(lane>>4)*4+reg (m)
        float tmax = 0.0f;
        if (j < D) {
            float bir = g_bias[j],          biz = g_bias[DP + j],     bin = g_bias[2 * DP + j];
            float bhr = g_bias[3 * DP + j], bhz = g_bias[4 * DP + j], bhn = g_bias[5 * DP + j];
            #pragma unroll
            for (int mf = 0; mf < 2; ++mf) {
                int m0 = wbase + mf * 16 + rowq;
                #pragma unroll
                for (int q = 0; q < 4; ++q) {
                    int m = m0 + q;
                    if (m < N_NODES) {
                        float hold = bf2f((short)hold_u[mf][q]);
                        float rr = fast_sigmoid(acc[0][mf][q] + bir + bhr);
                        float zz = fast_sigmoid(acc[1][mf][q] + biz + bhz);
                        float nn = fast_tanh(acc[2][mf][q] + bin + rr * (acc[3][mf][q] + bhn));
                        float hv2 = (1.0f - zz) * nn + zz * hold;
                        hnext[(size_t)m * KP + j] = __float2bfloat16(hv2);
                        if (hv2 > tmax) tmax = hv2;
                    }
                }
            }
            if (dopool) atomicMax(&pmax[j], __float_as_uint(tmax));
        }
    }

    if (dopool) {
        __syncthreads();
        for (int c = tid; c < D; c += 512) atomicMax(&pooled[c], pmax[c]);
    }
}

// ---------------- logits + softmax ----------------
__global__ void head_kernel(const unsigned int* __restrict__ pooled,
                            const float* __restrict__ cls_w,
                            const float* __restrict__ cls_b,
                            float* __restrict__ out) {
    if (threadIdx.x == 0) {
        float l0 = cls_b[0], l1 = cls_b[1];
        for (int d = 0; d < D; ++d) {
            float p = __uint_as_float(pooled[d]);
            l0 += p * cls_w[d];
            l1 += p * cls_w[D + d];
        }
        float mx = l0 > l1 ? l0 : l1;
        float e0 = expf(l0 - mx), e1 = expf(l1 - mx);
        out[0] = e0 / (e0 + e1);
        out[1] = e1 / (e0 + e1);
    }
}

extern "C" void kernel_launch(void* const* d_in, const int* in_sizes, int n_in,
                              void* d_out, int out_size, void* d_ws, size_t ws_size,
                              hipStream_t stream) {
    const float* x     = (const float*)d_in[0];
    const float* W     = (const float*)d_in[1];
    const float* w_ih  = (const float*)d_in[2];
    const float* w_hh  = (const float*)d_in[3];
    const float* b_ih  = (const float*)d_in[4];
    const float* b_hh  = (const float*)d_in[5];
    const float* cls_w = (const float*)d_in[6];
    const float* cls_b = (const float*)d_in[7];
    const int*   ei    = (const int*)d_in[8];
    const int* src = ei;
    const int* dst = ei + N_EDGES;

    const size_t ROWB = (size_t)N_PAD * KP;     // bf16 elements per buffer
    __hip_bfloat16* hA   = (__hip_bfloat16*)d_ws;
    __hip_bfloat16* hB   = hA + ROWB;
    __hip_bfloat16* Ascr = hB + ROWB;           // aggregated-message scratch (3rd buffer)
    int* cnt    = (int*)(Ascr + ROWB);
    int* incl   = cnt + N_NODES;
    int* bsum   = incl + N_NODES;
    int* off    = bsum + 128;
    int* cursor = off + N_NODES + 1;
    int* esrc   = cursor + N_NODES;
    unsigned int* pooled = (unsigned int*)(esrc + N_EDGES);

    // CSR build (once per call; edges are step-invariant)
    hipMemsetAsync(cnt, 0, N_NODES * sizeof(int), stream);
    count_kernel<<<(N_EDGES + 255) / 256, 256, 0, stream>>>(dst, cnt);
    scan1<<<NB_SCAN, SCAN_B, 0, stream>>>(cnt, incl, bsum);
    scan3<<<(N_NODES + 255) / 256, 256, 0, stream>>>(cnt, incl, bsum, off, cursor);
    fill_kernel<<<(N_EDGES + 255) / 256, 256, 0, stream>>>(src, dst, cursor, esrc);

    // weight prep (one kernel: fragment permute + Wc fold + bias)
    wconv_kernel<<<WCONV_BLOCKS + 5, 256, 0, stream>>>(W, w_ih, w_hh, b_ih, b_hh);

    pad_kernel<<<(int)(ROWB / 256), 256, 0, stream>>>(x, hA);
    // hB fully zeroed once: (a) gather's clamped batches read zero-row N_NODES on
    // odd steps, (b) cols 200..223 stay zero forever -> hv t=6 is a plain load.
    hipMemsetAsync(hB, 0, ROWB * sizeof(__hip_bfloat16), stream);
    hipMemsetAsync(pooled, 0, D * sizeof(unsigned int), stream);

    __hip_bfloat16* hcur = hA;
    __hip_bfloat16* hnext = hB;
    for (int s = 0; s < NUM_STEPS; ++s) {
        gather_kernel<<<N_PAD / 32, 256, 0, stream>>>(hcur, Ascr, off, esrc);
        gemm_gru<<<GRU_GRID, 512, 0, stream>>>(hcur, Ascr, hnext, pooled, s);
        __hip_bfloat16* t = hcur; hcur = hnext; hnext = t;
    }
    head_kernel<<<1, 64, 0, stream>>>(pooled, cls_w, cls_b, (float*)d_out);
}